// Round 15
// baseline (1411.104 us; speedup 1.0000x reference)
//
#include <hip/hip_runtime.h>

// B=64,K=64 -> 4096 (b,k) blocks; L=128 rows; D=128; H=256; 6 layers.
// 512-thread WGs, ~65.5 KB LDS -> 2 WGs/CU co-resident = 16 waves/CU.
// R15 = R14 with staging moved to global_load_lds (direct global->LDS, zero data
// VGPRs): R11/R14's 245MB one-time scratch spill = sim accs spilled across the
// h=1 restage (8 float4 staging regs + 32 live accs > 64-VGPR budget under the
// 64-AGPR MLP reservation). Pre-swizzled global source keeps LDS bit-identical.
// [128][64] f32 half-tile, float4-chunk addr (dwords), 4-bit XOR swizzle:
#define HID4(r,c4) ((r)*64 + ((((c4) ^ ((r)&15))) << 2))
// fp16 x-buffer [128][256] over the two half-tiles, swizzled on 8-elem (16B) chunks:
#define XIDX(r,c)  ((r)*256 + (((((c)>>3) ^ ((r)&7))) << 3) + ((c)&7))

typedef _Float16 half_t;
typedef __attribute__((ext_vector_type(8))) _Float16 f16x8;
typedef __attribute__((ext_vector_type(4))) float f32x4;

__device__ __forceinline__ float tanh_fast(float x){
    float e = __expf(2.0f * x);
    return 1.0f - 2.0f / (e + 1.0f);
}

// 8 fp32 -> f16x8 (RNE)
__device__ __forceinline__ f16x8 cvt8(float4 a, float4 b){
    f16x8 r;
    r[0]=(half_t)a.x; r[1]=(half_t)a.y; r[2]=(half_t)a.z; r[3]=(half_t)a.w;
    r[4]=(half_t)b.x; r[5]=(half_t)b.y; r[6]=(half_t)b.z; r[7]=(half_t)b.w;
    return r;
}

// async global->LDS, 16B per lane; lds dest = wave-uniform base + lane*16 (HW)
__device__ __forceinline__ void gload16(const void* g, void* l){
    __builtin_amdgcn_global_load_lds((const __attribute__((address_space(1))) unsigned int*)g,
                                     (__attribute__((address_space(3))) unsigned int*)l, 16, 0, 0);
}

__global__ __launch_bounds__(512, 4)   // 4 waves/EU min -> 128-reg unified cap; 2 WGs/CU co-reside
void fused_mlp_som(const float* __restrict__ ctx_in,   // (4096, 2, 128, 128) f32
                   const float* __restrict__ Ws,       // (6,256,256)
                   const float* __restrict__ bs,       // (6,256)
                   const float* __restrict__ Wout,     // (256)
                   const float* __restrict__ bout,     // (1)
                   float* __restrict__ out)            // (4096)
{
    extern __shared__ char smem[];
    float* S0     = (float*)smem;                 // [128][64] ctx k-half (32 KB)
    float* S1     = S0 + 128*64;                  // [128][64] ent k-half (32 KB)
    float* inv_cn = S1 + 128*64;                  // [128]
    float* inv_en = inv_cn + 128;                 // [128]
    int*   idxm   = (int*)(inv_en + 128);         // [128]
    float* redbuf = (float*)(idxm + 128);         // [8]
    half_t* xf    = (half_t*)smem;                // [128][256] fp16 over S0+S1, live after sim

    const int tid  = threadIdx.x;
    const int lane = tid & 63;
    const int bk   = blockIdx.x;

    const float*  gctx = ctx_in + (size_t)bk * 32768;
    const float*  gent = gctx + 16384;
    const float4* gc4  = (const float4*)gctx;     // [128][32] float4
    const float4* ge4  = (const float4*)gent;

    // norms: tid<256 -> ctx row chains, tid>=256 -> ent; (hf, nr) canonical
    const int isEnt = tid >> 8;
    const int hf    = tid & 1;
    const int nr    = (tid >> 1) & 127;
    float ns = 0.f;

    // sim: wave ti owns rows 16ti..16ti+15; lane tj owns cols {tj, tj+64}
    const int ti = tid >> 6;
    const int tj = tid & 63;
    const int l0 = ti * 16;
    float acc[16][2];
    #pragma unroll
    for (int i = 0; i < 16; ++i){ acc[i][0] = 0.f; acc[i][1] = 0.f; }

    // staging lane constants (pre-swizzled global source; see header comment)
    const int lr = lane >> 4;        // row-within-4
    const int lp = lane & 15;        // LDS chunk position

    #pragma unroll 1
    for (int h = 0; h < 2; ++h){
        if (h) __syncthreads();          // all phase-0 readers done before restage
        // ---- stage k-half h via global_load_lds: wave ti stages rows [16ti,16ti+16) ----
        #pragma unroll
        for (int it = 0; it < 4; ++it){
            const int rb  = 16*ti + 4*it;            // wave-uniform row base
            const int rsw = 4*it + lr;               // = r & 15 (row-within-16)
            const int gsw = lp ^ rsw;                // pre-swizzled global chunk
            gload16(gc4 + (rb + lr)*32 + 16*h + gsw, (char*)smem + rb*256);
            gload16(ge4 + (rb + lr)*32 + 16*h + gsw, (char*)smem + 32768 + rb*256);
        }
        __syncthreads();                 // drains vmcnt -> LDS data visible
        // ---- norm partial for this half (canonical 16-chunk chain) ----
        if (hf == h){
            const float* T = isEnt ? S1 : S0;
            #pragma unroll
            for (int u = 0; u < 16; ++u){
                float4 v = *(const float4*)&T[HID4(nr, u)];
                ns = fmaf(v.x, v.x, ns); ns = fmaf(v.y, v.y, ns);
                ns = fmaf(v.z, v.z, ns); ns = fmaf(v.w, v.w, ns);
            }
        }
        // ---- sim accumulate kc = 16h .. 16h+15 (canonical ascending-k xyzw chains) ----
        for (int kk = 0; kk < 16; ++kk){
            float4 e0 = *(const float4*)&S1[HID4(tj     , kk)];
            float4 e1 = *(const float4*)&S1[HID4(tj + 64, kk)];
            #pragma unroll
            for (int i = 0; i < 16; ++i){
                float4 a = *(const float4*)&S0[HID4(l0+i, kk)];  // wave-uniform: broadcast
                float s0 = acc[i][0], s1 = acc[i][1];
                s0 = fmaf(a.x,e0.x,s0); s0 = fmaf(a.y,e0.y,s0);
                s0 = fmaf(a.z,e0.z,s0); s0 = fmaf(a.w,e0.w,s0);
                s1 = fmaf(a.x,e1.x,s1); s1 = fmaf(a.y,e1.y,s1);
                s1 = fmaf(a.z,e1.z,s1); s1 = fmaf(a.w,e1.w,s1);
                acc[i][0] = s0; acc[i][1] = s1;
            }
        }
    }

    // ---- combine norm halves, publish ----
    ns += __shfl_xor(ns, 1);
    if (hf == 0){
        float inv = 1.0f / sqrtf(ns);
        if (isEnt) inv_en[nr] = inv; else inv_cn[nr] = inv;
    }
    __syncthreads();

    // ---- argmax: exact max+min-index lattice op; 64-lane butterfly ----
    #pragma unroll
    for (int i = 0; i < 16; ++i){
        float best = -1e38f; int bi = 0;
        #pragma unroll
        for (int j = 0; j < 2; ++j){
            int m = tj + 64*j;
            float v = acc[i][j] * inv_en[m];
            if (v > best || (v == best && m < bi)){ best = v; bi = m; }
        }
        #pragma unroll
        for (int s = 1; s < 64; s <<= 1){
            float ov = __shfl_xor(best, s);
            int   oi = __shfl_xor(bi,   s);
            if (ov > best || (ov == best && oi < bi)){ best = ov; bi = oi; }
        }
        if (tj == 0) idxm[l0 + i] = bi;
    }
    __syncthreads();

    // ---- x0 = [ctx_n | ent_n[idx]] fp16 over S0+S1, from GLOBAL (L2-hot), f16x8 writes ----
    {
        const int l = tid >> 2;          // 0..127
        const int q = tid & 3;           // 0,1: ctx col-halves; 2,3: ent col-halves
        const float4* src;
        float sc;
        int c0;
        if (q < 2){ src = (const float4*)(gctx + l*128 + 64*q);  sc = inv_cn[l]; c0 = 64*q; }
        else { int mi = idxm[l]; src = (const float4*)(gent + mi*128 + 64*(q-2)); sc = inv_en[mi]; c0 = 128 + 64*(q-2); }
        #pragma unroll
        for (int u = 0; u < 8; ++u){
            float4 va = src[2*u];
            float4 vb = src[2*u+1];
            f16x8 hv;
            hv[0]=(half_t)(va.x*sc); hv[1]=(half_t)(va.y*sc); hv[2]=(half_t)(va.z*sc); hv[3]=(half_t)(va.w*sc);
            hv[4]=(half_t)(vb.x*sc); hv[5]=(half_t)(vb.y*sc); hv[6]=(half_t)(vb.z*sc); hv[7]=(half_t)(vb.w*sc);
            int c = c0 + 8*u;            // chunk-aligned
            *(f16x8*)&xf[l*256 + ((((c>>3) ^ (l&7))) << 3)] = hv;
        }
    }
    __syncthreads();

    // ---- 6-layer MLP: fp16 single-product MFMA, 8 waves N-split-8 (R11/R14 exact) ----
    const int wv    = tid >> 6;              // 0..7
    const int lan15 = lane & 15;
    const int lq    = lane >> 4;
    const int n0    = 32*wv + lan15;
    const int n1    = n0 + 16;
    const int bno0  = n0 * 256;
    const int bno1  = n1 * 256;
    const int kb    = 8*lq;
    const int aBase = lan15*256;             // + mt*4096 + aoff

    #pragma unroll 1
    for (int layer = 0; layer < 6; ++layer){
        const float* WsL = Ws + layer*65536;

        f32x4 mac[8][2];
        #pragma unroll
        for (int mt = 0; mt < 8; ++mt){
            mac[mt][0] = (f32x4){0.f,0.f,0.f,0.f};
            mac[mt][1] = (f32x4){0.f,0.f,0.f,0.f};
        }

        #pragma unroll 1
        for (int ks = 0; ks < 8; ++ks){
            const int aoff = (((4*ks + lq) ^ (lan15 & 7)) << 3);
            // W frags: fp32 from L2 (hot), cvt inline; latency covered by 16 waves/CU
            f16x8 b0, b1;
            {
                const int kk = 32*ks + kb;
                float4 qa = *(const float4*)&WsL[bno0 + kk];
                float4 qb = *(const float4*)&WsL[bno0 + kk + 4];
                float4 qc = *(const float4*)&WsL[bno1 + kk];
                float4 qd = *(const float4*)&WsL[bno1 + kk + 4];
                b0 = cvt8(qa, qb);
                b1 = cvt8(qc, qd);
            }
            // batch 1: rows 0..63
            {
                f16x8 a[4];
                #pragma unroll
                for (int mt = 0; mt < 4; ++mt)
                    a[mt] = *(const f16x8*)&xf[aBase + mt*4096 + aoff];
                #pragma unroll
                for (int mt = 0; mt < 4; ++mt){
                    mac[mt][0] = __builtin_amdgcn_mfma_f32_16x16x32_f16(a[mt], b0, mac[mt][0], 0,0,0);
                    mac[mt][1] = __builtin_amdgcn_mfma_f32_16x16x32_f16(a[mt], b1, mac[mt][1], 0,0,0);
                }
            }
            // batch 2: rows 64..127
            {
                f16x8 a[4];
                #pragma unroll
                for (int mt = 0; mt < 4; ++mt)
                    a[mt] = *(const f16x8*)&xf[aBase + (mt+4)*4096 + aoff];
                #pragma unroll
                for (int mt = 0; mt < 4; ++mt){
                    mac[mt+4][0] = __builtin_amdgcn_mfma_f32_16x16x32_f16(a[mt], b0, mac[mt+4][0], 0,0,0);
                    mac[mt+4][1] = __builtin_amdgcn_mfma_f32_16x16x32_f16(a[mt], b1, mac[mt+4][1], 0,0,0);
                }
            }
        }
        __syncthreads();   // all waves done reading xf

        if (layer < 5){
            float bias0 = bs[layer*256 + n0];
            float bias1 = bs[layer*256 + n1];
            #pragma unroll
            for (int mt = 0; mt < 8; ++mt){
                #pragma unroll
                for (int r = 0; r < 4; ++r){
                    int row = 16*mt + 4*lq + r;      // C/D: col=lane&15, row=(lane>>4)*4+reg
                    xf[XIDX(row, n0)] = (half_t)tanh_fast(mac[mt][0][r] + bias0);
                    xf[XIDX(row, n1)] = (half_t)tanh_fast(mac[mt][1][r] + bias1);
                }
            }
            __syncthreads();
        } else {
            float bias0 = bs[5*256 + n0];
            float bias1 = bs[5*256 + n1];
            float w0 = Wout[n0];
            float w1 = Wout[n1];
            float part = 0.f;
            #pragma unroll
            for (int mt = 0; mt < 8; ++mt){
                #pragma unroll
                for (int r = 0; r < 4; ++r){
                    part = fmaf(tanh_fast(mac[mt][0][r] + bias0), w0, part);
                    part = fmaf(tanh_fast(mac[mt][1][r] + bias1), w1, part);
                }
            }
            #pragma unroll
            for (int s = 1; s < 64; s <<= 1) part += __shfl_xor(part, s);
            if (lane == 0) redbuf[wv] = part;
            __syncthreads();
            if (tid == 0){
                float s = 0.f;
                #pragma unroll
                for (int i = 0; i < 8; ++i) s += redbuf[i];
                out[bk] = s + 128.0f * bout[0];
            }
        }
    }
}

extern "C" void kernel_launch(void* const* d_in, const int* in_sizes, int n_in,
                              void* d_out, int out_size, void* d_ws, size_t ws_size,
                              hipStream_t stream)
{
    (void)in_sizes; (void)n_in; (void)out_size; (void)d_ws; (void)ws_size;
    const float* ctx  = (const float*)d_in[0];
    const float* Ws   = (const float*)d_in[1];
    const float* bs   = (const float*)d_in[2];
    const float* Wout = (const float*)d_in[3];
    const float* bout = (const float*)d_in[4];
    float* out = (float*)d_out;

    const int smem_bytes = 128*64*4*2 + 128*4 + 128*4 + 128*4 + 8*4;  // 67104 B -> 2 WGs/CU
    hipFuncSetAttribute(reinterpret_cast<const void*>(fused_mlp_som),
                        hipFuncAttributeMaxDynamicSharedMemorySize, smem_bytes);
    fused_mlp_som<<<dim3(4096), dim3(512), smem_bytes, stream>>>(ctx, Ws, bs, Wout, bout, out);
}

// Round 16
// 1393.303 us; speedup vs baseline: 1.0128x; 1.0128x over previous
//
#include <hip/hip_runtime.h>

// B=64,K=64 -> 4096 (b,k) blocks; L=128 rows; D=128; H=256; 6 layers.
// 512-thread WGs, ~65.5 KB LDS -> 2 WGs/CU co-resident = 16 waves/CU.
// R16 = R15 with the MLP ks-body restructured for minimal register liveness:
// pairwise W load+cvt (transient 16->8), A-frags in 4 batches of 2 rows, and
// sched_barrier(0) fences so the scheduler can't re-merge loads into one
// high-liveness block. Spill accounting: 254MB = 5 dw/thread/layer (R11/14/15)
// vs 57MB (R13 small-MLP) -> spill lives in the MLP loop under the 64-VGPR
// residue left by the 64-AGPR mac reservation.
// [128][64] f32 half-tile, float4-chunk addr (dwords), 4-bit XOR swizzle:
#define HID4(r,c4) ((r)*64 + ((((c4) ^ ((r)&15))) << 2))
// fp16 x-buffer [128][256] over the two half-tiles, swizzled on 8-elem (16B) chunks:
#define XIDX(r,c)  ((r)*256 + (((((c)>>3) ^ ((r)&7))) << 3) + ((c)&7))

typedef _Float16 half_t;
typedef __attribute__((ext_vector_type(8))) _Float16 f16x8;
typedef __attribute__((ext_vector_type(4))) float f32x4;

__device__ __forceinline__ float tanh_fast(float x){
    float e = __expf(2.0f * x);
    return 1.0f - 2.0f / (e + 1.0f);
}

// 8 fp32 -> f16x8 (RNE)
__device__ __forceinline__ f16x8 cvt8(float4 a, float4 b){
    f16x8 r;
    r[0]=(half_t)a.x; r[1]=(half_t)a.y; r[2]=(half_t)a.z; r[3]=(half_t)a.w;
    r[4]=(half_t)b.x; r[5]=(half_t)b.y; r[6]=(half_t)b.z; r[7]=(half_t)b.w;
    return r;
}

// async global->LDS, 16B per lane; lds dest = wave-uniform base + lane*16 (HW)
__device__ __forceinline__ void gload16(const void* g, void* l){
    __builtin_amdgcn_global_load_lds((const __attribute__((address_space(1))) unsigned int*)g,
                                     (__attribute__((address_space(3))) unsigned int*)l, 16, 0, 0);
}

__global__ __launch_bounds__(512, 4)   // 4 waves/EU min -> 128-reg unified cap; 2 WGs/CU co-reside
void fused_mlp_som(const float* __restrict__ ctx_in,   // (4096, 2, 128, 128) f32
                   const float* __restrict__ Ws,       // (6,256,256)
                   const float* __restrict__ bs,       // (6,256)
                   const float* __restrict__ Wout,     // (256)
                   const float* __restrict__ bout,     // (1)
                   float* __restrict__ out)            // (4096)
{
    extern __shared__ char smem[];
    float* S0     = (float*)smem;                 // [128][64] ctx k-half (32 KB)
    float* S1     = S0 + 128*64;                  // [128][64] ent k-half (32 KB)
    float* inv_cn = S1 + 128*64;                  // [128]
    float* inv_en = inv_cn + 128;                 // [128]
    int*   idxm   = (int*)(inv_en + 128);         // [128]
    float* redbuf = (float*)(idxm + 128);         // [8]
    half_t* xf    = (half_t*)smem;                // [128][256] fp16 over S0+S1, live after sim

    const int tid  = threadIdx.x;
    const int lane = tid & 63;
    const int bk   = blockIdx.x;

    const float*  gctx = ctx_in + (size_t)bk * 32768;
    const float*  gent = gctx + 16384;
    const float4* gc4  = (const float4*)gctx;     // [128][32] float4
    const float4* ge4  = (const float4*)gent;

    // norms: tid<256 -> ctx row chains, tid>=256 -> ent; (hf, nr) canonical
    const int isEnt = tid >> 8;
    const int hf    = tid & 1;
    const int nr    = (tid >> 1) & 127;
    float ns = 0.f;

    // sim: wave ti owns rows 16ti..16ti+15; lane tj owns cols {tj, tj+64}
    const int ti = tid >> 6;
    const int tj = tid & 63;
    const int l0 = ti * 16;
    float acc[16][2];
    #pragma unroll
    for (int i = 0; i < 16; ++i){ acc[i][0] = 0.f; acc[i][1] = 0.f; }

    // staging lane constants (pre-swizzled global source)
    const int lr = lane >> 4;        // row-within-4
    const int lp = lane & 15;        // LDS chunk position

    #pragma unroll 1
    for (int h = 0; h < 2; ++h){
        if (h) __syncthreads();          // all phase-0 readers done before restage
        // ---- stage k-half h via global_load_lds: wave ti stages rows [16ti,16ti+16) ----
        #pragma unroll
        for (int it = 0; it < 4; ++it){
            const int rb  = 16*ti + 4*it;            // wave-uniform row base
            const int rsw = 4*it + lr;               // = r & 15 (row-within-16)
            const int gsw = lp ^ rsw;                // pre-swizzled global chunk
            gload16(gc4 + (rb + lr)*32 + 16*h + gsw, (char*)smem + rb*256);
            gload16(ge4 + (rb + lr)*32 + 16*h + gsw, (char*)smem + 32768 + rb*256);
        }
        __syncthreads();                 // drains vmcnt -> LDS data visible
        // ---- norm partial for this half (canonical 16-chunk chain) ----
        if (hf == h){
            const float* T = isEnt ? S1 : S0;
            #pragma unroll
            for (int u = 0; u < 16; ++u){
                float4 v = *(const float4*)&T[HID4(nr, u)];
                ns = fmaf(v.x, v.x, ns); ns = fmaf(v.y, v.y, ns);
                ns = fmaf(v.z, v.z, ns); ns = fmaf(v.w, v.w, ns);
            }
        }
        // ---- sim accumulate kc = 16h .. 16h+15 (canonical ascending-k xyzw chains) ----
        for (int kk = 0; kk < 16; ++kk){
            float4 e0 = *(const float4*)&S1[HID4(tj     , kk)];
            float4 e1 = *(const float4*)&S1[HID4(tj + 64, kk)];
            #pragma unroll
            for (int i = 0; i < 16; ++i){
                float4 a = *(const float4*)&S0[HID4(l0+i, kk)];  // wave-uniform: broadcast
                float s0 = acc[i][0], s1 = acc[i][1];
                s0 = fmaf(a.x,e0.x,s0); s0 = fmaf(a.y,e0.y,s0);
                s0 = fmaf(a.z,e0.z,s0); s0 = fmaf(a.w,e0.w,s0);
                s1 = fmaf(a.x,e1.x,s1); s1 = fmaf(a.y,e1.y,s1);
                s1 = fmaf(a.z,e1.z,s1); s1 = fmaf(a.w,e1.w,s1);
                acc[i][0] = s0; acc[i][1] = s1;
            }
        }
    }

    // ---- combine norm halves, publish ----
    ns += __shfl_xor(ns, 1);
    if (hf == 0){
        float inv = 1.0f / sqrtf(ns);
        if (isEnt) inv_en[nr] = inv; else inv_cn[nr] = inv;
    }
    __syncthreads();

    // ---- argmax: exact max+min-index lattice op; 64-lane butterfly ----
    #pragma unroll
    for (int i = 0; i < 16; ++i){
        float best = -1e38f; int bi = 0;
        #pragma unroll
        for (int j = 0; j < 2; ++j){
            int m = tj + 64*j;
            float v = acc[i][j] * inv_en[m];
            if (v > best || (v == best && m < bi)){ best = v; bi = m; }
        }
        #pragma unroll
        for (int s = 1; s < 64; s <<= 1){
            float ov = __shfl_xor(best, s);
            int   oi = __shfl_xor(bi,   s);
            if (ov > best || (ov == best && oi < bi)){ best = ov; bi = oi; }
        }
        if (tj == 0) idxm[l0 + i] = bi;
    }
    __syncthreads();

    // ---- x0 = [ctx_n | ent_n[idx]] fp16 over S0+S1, from GLOBAL (L2-hot), f16x8 writes ----
    {
        const int l = tid >> 2;          // 0..127
        const int q = tid & 3;           // 0,1: ctx col-halves; 2,3: ent col-halves
        const float4* src;
        float sc;
        int c0;
        if (q < 2){ src = (const float4*)(gctx + l*128 + 64*q);  sc = inv_cn[l]; c0 = 64*q; }
        else { int mi = idxm[l]; src = (const float4*)(gent + mi*128 + 64*(q-2)); sc = inv_en[mi]; c0 = 128 + 64*(q-2); }
        #pragma unroll
        for (int u = 0; u < 8; ++u){
            float4 va = src[2*u];
            float4 vb = src[2*u+1];
            f16x8 hv;
            hv[0]=(half_t)(va.x*sc); hv[1]=(half_t)(va.y*sc); hv[2]=(half_t)(va.z*sc); hv[3]=(half_t)(va.w*sc);
            hv[4]=(half_t)(vb.x*sc); hv[5]=(half_t)(vb.y*sc); hv[6]=(half_t)(vb.z*sc); hv[7]=(half_t)(vb.w*sc);
            int c = c0 + 8*u;            // chunk-aligned
            *(f16x8*)&xf[l*256 + ((((c>>3) ^ (l&7))) << 3)] = hv;
        }
    }
    __syncthreads();

    // ---- 6-layer MLP: fp16 single-product MFMA, 8 waves N-split-8 ----
    // ks-body restructured for minimal liveness (see header): pairwise W,
    // 2-row A-batches, sched_barrier(0) fences. Per-mac K-chain unchanged.
    const int wv    = tid >> 6;              // 0..7
    const int lan15 = lane & 15;
    const int lq    = lane >> 4;
    const int n0    = 32*wv + lan15;
    const int n1    = n0 + 16;
    const int bno0  = n0 * 256;
    const int bno1  = n1 * 256;
    const int kb    = 8*lq;
    const int aBase = lan15*256;             // + mt*4096 + aoff

    #pragma unroll 1
    for (int layer = 0; layer < 6; ++layer){
        const float* WsL = Ws + layer*65536;

        f32x4 mac[8][2];
        #pragma unroll
        for (int mt = 0; mt < 8; ++mt){
            mac[mt][0] = (f32x4){0.f,0.f,0.f,0.f};
            mac[mt][1] = (f32x4){0.f,0.f,0.f,0.f};
        }

        #pragma unroll 1
        for (int ks = 0; ks < 8; ++ks){
            const int aoff = (((4*ks + lq) ^ (lan15 & 7)) << 3);
            const int kk   = 32*ks + kb;
            f16x8 b0, b1;
            {
                float4 qa = *(const float4*)&WsL[bno0 + kk];
                float4 qb = *(const float4*)&WsL[bno0 + kk + 4];
                b0 = cvt8(qa, qb);
            }
            __builtin_amdgcn_sched_barrier(0);
            {
                float4 qc = *(const float4*)&WsL[bno1 + kk];
                float4 qd = *(const float4*)&WsL[bno1 + kk + 4];
                b1 = cvt8(qc, qd);
            }
            __builtin_amdgcn_sched_barrier(0);
            #pragma unroll
            for (int bt = 0; bt < 4; ++bt){
                f16x8 a0 = *(const f16x8*)&xf[aBase + (2*bt  )*4096 + aoff];
                f16x8 a1 = *(const f16x8*)&xf[aBase + (2*bt+1)*4096 + aoff];
                mac[2*bt  ][0] = __builtin_amdgcn_mfma_f32_16x16x32_f16(a0, b0, mac[2*bt  ][0], 0,0,0);
                mac[2*bt  ][1] = __builtin_amdgcn_mfma_f32_16x16x32_f16(a0, b1, mac[2*bt  ][1], 0,0,0);
                mac[2*bt+1][0] = __builtin_amdgcn_mfma_f32_16x16x32_f16(a1, b0, mac[2*bt+1][0], 0,0,0);
                mac[2*bt+1][1] = __builtin_amdgcn_mfma_f32_16x16x32_f16(a1, b1, mac[2*bt+1][1], 0,0,0);
                __builtin_amdgcn_sched_barrier(0);
            }
        }
        __syncthreads();   // all waves done reading xf

        if (layer < 5){
            float bias0 = bs[layer*256 + n0];
            float bias1 = bs[layer*256 + n1];
            #pragma unroll
            for (int mt = 0; mt < 8; ++mt){
                #pragma unroll
                for (int r = 0; r < 4; ++r){
                    int row = 16*mt + 4*lq + r;      // C/D: col=lane&15, row=(lane>>4)*4+reg
                    xf[XIDX(row, n0)] = (half_t)tanh_fast(mac[mt][0][r] + bias0);
                    xf[XIDX(row, n1)] = (half_t)tanh_fast(mac[mt][1][r] + bias1);
                }
            }
            __syncthreads();
        } else {
            float bias0 = bs[5*256 + n0];
            float bias1 = bs[5*256 + n1];
            float w0 = Wout[n0];
            float w1 = Wout[n1];
            float part = 0.f;
            #pragma unroll
            for (int mt = 0; mt < 8; ++mt){
                #pragma unroll
                for (int r = 0; r < 4; ++r){
                    part = fmaf(tanh_fast(mac[mt][0][r] + bias0), w0, part);
                    part = fmaf(tanh_fast(mac[mt][1][r] + bias1), w1, part);
                }
            }
            #pragma unroll
            for (int s = 1; s < 64; s <<= 1) part += __shfl_xor(part, s);
            if (lane == 0) redbuf[wv] = part;
            __syncthreads();
            if (tid == 0){
                float s = 0.f;
                #pragma unroll
                for (int i = 0; i < 8; ++i) s += redbuf[i];
                out[bk] = s + 128.0f * bout[0];
            }
        }
    }
}

extern "C" void kernel_launch(void* const* d_in, const int* in_sizes, int n_in,
                              void* d_out, int out_size, void* d_ws, size_t ws_size,
                              hipStream_t stream)
{
    (void)in_sizes; (void)n_in; (void)out_size; (void)d_ws; (void)ws_size;
    const float* ctx  = (const float*)d_in[0];
    const float* Ws   = (const float*)d_in[1];
    const float* bs   = (const float*)d_in[2];
    const float* Wout = (const float*)d_in[3];
    const float* bout = (const float*)d_in[4];
    float* out = (float*)d_out;

    const int smem_bytes = 128*64*4*2 + 128*4 + 128*4 + 128*4 + 8*4;  // 67104 B -> 2 WGs/CU
    hipFuncSetAttribute(reinterpret_cast<const void*>(fused_mlp_som),
                        hipFuncAttributeMaxDynamicSharedMemorySize, smem_bytes);
    fused_mlp_som<<<dim3(4096), dim3(512), smem_bytes, stream>>>(ctx, Ws, bs, Wout, bout, out);
}

// Round 17
// 1320.561 us; speedup vs baseline: 1.0686x; 1.0551x over previous
//
#include <hip/hip_runtime.h>

// B=64,K=64 -> 4096 (b,k) blocks; L=128 rows; D=128; H=256; 6 layers.
// 512-thread WGs, ~65.5 KB LDS -> 2 WGs/CU co-resident = 16 waves/CU.
// R17 = R16 with sim reverted to the 8x4 tile (R11's exact canonical body):
// LDS-pipe accounting says sim 16x2 = 576 b128/thread vs 8x4 = 384 (optimal
// (R+C)/4RC), and the LDS pipe (~830us/CU total) is the wall — not the scratch
// spill (R13/R16 proved WRITE_SIZE doesn't move dur). gload_lds staging (R15)
// keeps restage liveness at ~40 regs so 8x4's ~60-reg loop fits the 64-VGPR
// residue under the 64-AGPR MLP reservation.
// [128][64] f32 half-tile, float4-chunk addr (dwords), 4-bit XOR swizzle:
#define HID4(r,c4) ((r)*64 + ((((c4) ^ ((r)&15))) << 2))
// fp16 x-buffer [128][256] over the two half-tiles, swizzled on 8-elem (16B) chunks:
#define XIDX(r,c)  ((r)*256 + (((((c)>>3) ^ ((r)&7))) << 3) + ((c)&7))

typedef _Float16 half_t;
typedef __attribute__((ext_vector_type(8))) _Float16 f16x8;
typedef __attribute__((ext_vector_type(4))) float f32x4;

__device__ __forceinline__ float tanh_fast(float x){
    float e = __expf(2.0f * x);
    return 1.0f - 2.0f / (e + 1.0f);
}

// 8 fp32 -> f16x8 (RNE)
__device__ __forceinline__ f16x8 cvt8(float4 a, float4 b){
    f16x8 r;
    r[0]=(half_t)a.x; r[1]=(half_t)a.y; r[2]=(half_t)a.z; r[3]=(half_t)a.w;
    r[4]=(half_t)b.x; r[5]=(half_t)b.y; r[6]=(half_t)b.z; r[7]=(half_t)b.w;
    return r;
}

// async global->LDS, 16B per lane; lds dest = wave-uniform base + lane*16 (HW)
__device__ __forceinline__ void gload16(const void* g, void* l){
    __builtin_amdgcn_global_load_lds((const __attribute__((address_space(1))) unsigned int*)g,
                                     (__attribute__((address_space(3))) unsigned int*)l, 16, 0, 0);
}

__global__ __launch_bounds__(512, 4)   // 4 waves/EU min -> 128-reg unified cap; 2 WGs/CU co-reside
void fused_mlp_som(const float* __restrict__ ctx_in,   // (4096, 2, 128, 128) f32
                   const float* __restrict__ Ws,       // (6,256,256)
                   const float* __restrict__ bs,       // (6,256)
                   const float* __restrict__ Wout,     // (256)
                   const float* __restrict__ bout,     // (1)
                   float* __restrict__ out)            // (4096)
{
    extern __shared__ char smem[];
    float* S0     = (float*)smem;                 // [128][64] ctx k-half (32 KB)
    float* S1     = S0 + 128*64;                  // [128][64] ent k-half (32 KB)
    float* inv_cn = S1 + 128*64;                  // [128]
    float* inv_en = inv_cn + 128;                 // [128]
    int*   idxm   = (int*)(inv_en + 128);         // [128]
    float* redbuf = (float*)(idxm + 128);         // [8]
    half_t* xf    = (half_t*)smem;                // [128][256] fp16 over S0+S1, live after sim

    const int tid  = threadIdx.x;
    const int lane = tid & 63;
    const int bk   = blockIdx.x;
    const int wid  = tid >> 6;       // wave index 0..7 (staging + MLP)

    const float*  gctx = ctx_in + (size_t)bk * 32768;
    const float*  gent = gctx + 16384;
    const float4* gc4  = (const float4*)gctx;     // [128][32] float4
    const float4* ge4  = (const float4*)gent;

    // norms: tid<256 -> ctx row chains, tid>=256 -> ent; (hf, nr) canonical
    const int isEnt = tid >> 8;
    const int hf    = tid & 1;
    const int nr    = (tid >> 1) & 127;
    float ns = 0.f;

    // sim: thread (ti,tj): rows 8ti..8ti+7, cols {tj,+32,+64,+96} (R11 canonical 8x4)
    const int ti = tid >> 5;
    const int tj = tid & 31;
    const int l0 = ti * 8;
    float acc[8][4];
    #pragma unroll
    for (int i = 0; i < 8; ++i)
        #pragma unroll
        for (int j = 0; j < 4; ++j) acc[i][j] = 0.f;

    // staging lane constants (pre-swizzled global source)
    const int lr = lane >> 4;        // row-within-4
    const int lp = lane & 15;        // LDS chunk position

    #pragma unroll 1
    for (int h = 0; h < 2; ++h){
        if (h) __syncthreads();          // all phase-0 readers done before restage
        // ---- stage k-half h via global_load_lds: wave wid stages rows [16wid,16wid+16) ----
        #pragma unroll
        for (int it = 0; it < 4; ++it){
            const int rb  = 16*wid + 4*it;           // wave-uniform row base
            const int rsw = 4*it + lr;               // = r & 15 (row-within-16)
            const int gsw = lp ^ rsw;                // pre-swizzled global chunk
            gload16(gc4 + (rb + lr)*32 + 16*h + gsw, (char*)smem + rb*256);
            gload16(ge4 + (rb + lr)*32 + 16*h + gsw, (char*)smem + 32768 + rb*256);
        }
        __syncthreads();                 // drains vmcnt -> LDS data visible
        // ---- norm partial for this half (canonical 16-chunk chain) ----
        if (hf == h){
            const float* T = isEnt ? S1 : S0;
            #pragma unroll
            for (int u = 0; u < 16; ++u){
                float4 v = *(const float4*)&T[HID4(nr, u)];
                ns = fmaf(v.x, v.x, ns); ns = fmaf(v.y, v.y, ns);
                ns = fmaf(v.z, v.z, ns); ns = fmaf(v.w, v.w, ns);
            }
        }
        // ---- sim accumulate kc = 16h .. 16h+15 (R11 canonical chains) ----
        for (int kk = 0; kk < 16; ++kk){
            float4 e0 = *(const float4*)&S1[HID4(tj     , kk)];
            float4 e1 = *(const float4*)&S1[HID4(tj + 32, kk)];
            float4 e2 = *(const float4*)&S1[HID4(tj + 64, kk)];
            float4 e3 = *(const float4*)&S1[HID4(tj + 96, kk)];
            #pragma unroll
            for (int i = 0; i < 8; ++i){
                float4 a = *(const float4*)&S0[HID4(l0+i, kk)];
                acc[i][0] = fmaf(a.x,e0.x,acc[i][0]); acc[i][0] = fmaf(a.y,e0.y,acc[i][0]);
                acc[i][0] = fmaf(a.z,e0.z,acc[i][0]); acc[i][0] = fmaf(a.w,e0.w,acc[i][0]);
                acc[i][1] = fmaf(a.x,e1.x,acc[i][1]); acc[i][1] = fmaf(a.y,e1.y,acc[i][1]);
                acc[i][1] = fmaf(a.z,e1.z,acc[i][1]); acc[i][1] = fmaf(a.w,e1.w,acc[i][1]);
                acc[i][2] = fmaf(a.x,e2.x,acc[i][2]); acc[i][2] = fmaf(a.y,e2.y,acc[i][2]);
                acc[i][2] = fmaf(a.z,e2.z,acc[i][2]); acc[i][2] = fmaf(a.w,e2.w,acc[i][2]);
                acc[i][3] = fmaf(a.x,e3.x,acc[i][3]); acc[i][3] = fmaf(a.y,e3.y,acc[i][3]);
                acc[i][3] = fmaf(a.z,e3.z,acc[i][3]); acc[i][3] = fmaf(a.w,e3.w,acc[i][3]);
            }
        }
    }

    // ---- combine norm halves, publish ----
    ns += __shfl_xor(ns, 1);
    if (hf == 0){
        float inv = 1.0f / sqrtf(ns);
        if (isEnt) inv_en[nr] = inv; else inv_cn[nr] = inv;
    }
    __syncthreads();

    // ---- argmax (R11 canonical: j<4, 32-lane butterfly) ----
    #pragma unroll
    for (int i = 0; i < 8; ++i){
        float best = -1e38f; int bi = 0;
        #pragma unroll
        for (int j = 0; j < 4; ++j){
            int m = tj + 32*j;
            float v = acc[i][j] * inv_en[m];
            if (v > best || (v == best && m < bi)){ best = v; bi = m; }
        }
        #pragma unroll
        for (int s = 1; s < 32; s <<= 1){
            float ov = __shfl_xor(best, s);
            int   oi = __shfl_xor(bi,   s);
            if (ov > best || (ov == best && oi < bi)){ best = ov; bi = oi; }
        }
        if (tj == 0) idxm[l0 + i] = bi;
    }
    __syncthreads();

    // ---- x0 = [ctx_n | ent_n[idx]] fp16 over S0+S1, from GLOBAL (L2-hot), f16x8 writes ----
    {
        const int l = tid >> 2;          // 0..127
        const int q = tid & 3;           // 0,1: ctx col-halves; 2,3: ent col-halves
        const float4* src;
        float sc;
        int c0;
        if (q < 2){ src = (const float4*)(gctx + l*128 + 64*q);  sc = inv_cn[l]; c0 = 64*q; }
        else { int mi = idxm[l]; src = (const float4*)(gent + mi*128 + 64*(q-2)); sc = inv_en[mi]; c0 = 128 + 64*(q-2); }
        #pragma unroll
        for (int u = 0; u < 8; ++u){
            float4 va = src[2*u];
            float4 vb = src[2*u+1];
            f16x8 hv;
            hv[0]=(half_t)(va.x*sc); hv[1]=(half_t)(va.y*sc); hv[2]=(half_t)(va.z*sc); hv[3]=(half_t)(va.w*sc);
            hv[4]=(half_t)(vb.x*sc); hv[5]=(half_t)(vb.y*sc); hv[6]=(half_t)(vb.z*sc); hv[7]=(half_t)(vb.w*sc);
            int c = c0 + 8*u;            // chunk-aligned
            *(f16x8*)&xf[l*256 + ((((c>>3) ^ (l&7))) << 3)] = hv;
        }
    }
    __syncthreads();

    // ---- 6-layer MLP: fp16 single-product MFMA, 8 waves N-split-8 (R16 exact) ----
    const int lan15 = lane & 15;
    const int lq    = lane >> 4;
    const int n0    = 32*wid + lan15;
    const int n1    = n0 + 16;
    const int bno0  = n0 * 256;
    const int bno1  = n1 * 256;
    const int kb    = 8*lq;
    const int aBase = lan15*256;             // + mt*4096 + aoff

    #pragma unroll 1
    for (int layer = 0; layer < 6; ++layer){
        const float* WsL = Ws + layer*65536;

        f32x4 mac[8][2];
        #pragma unroll
        for (int mt = 0; mt < 8; ++mt){
            mac[mt][0] = (f32x4){0.f,0.f,0.f,0.f};
            mac[mt][1] = (f32x4){0.f,0.f,0.f,0.f};
        }

        #pragma unroll 1
        for (int ks = 0; ks < 8; ++ks){
            const int aoff = (((4*ks + lq) ^ (lan15 & 7)) << 3);
            const int kk   = 32*ks + kb;
            f16x8 b0, b1;
            {
                float4 qa = *(const float4*)&WsL[bno0 + kk];
                float4 qb = *(const float4*)&WsL[bno0 + kk + 4];
                b0 = cvt8(qa, qb);
            }
            __builtin_amdgcn_sched_barrier(0);
            {
                float4 qc = *(const float4*)&WsL[bno1 + kk];
                float4 qd = *(const float4*)&WsL[bno1 + kk + 4];
                b1 = cvt8(qc, qd);
            }
            __builtin_amdgcn_sched_barrier(0);
            #pragma unroll
            for (int bt = 0; bt < 4; ++bt){
                f16x8 a0 = *(const f16x8*)&xf[aBase + (2*bt  )*4096 + aoff];
                f16x8 a1 = *(const f16x8*)&xf[aBase + (2*bt+1)*4096 + aoff];
                mac[2*bt  ][0] = __builtin_amdgcn_mfma_f32_16x16x32_f16(a0, b0, mac[2*bt  ][0], 0,0,0);
                mac[2*bt  ][1] = __builtin_amdgcn_mfma_f32_16x16x32_f16(a0, b1, mac[2*bt  ][1], 0,0,0);
                mac[2*bt+1][0] = __builtin_amdgcn_mfma_f32_16x16x32_f16(a1, b0, mac[2*bt+1][0], 0,0,0);
                mac[2*bt+1][1] = __builtin_amdgcn_mfma_f32_16x16x32_f16(a1, b1, mac[2*bt+1][1], 0,0,0);
                __builtin_amdgcn_sched_barrier(0);
            }
        }
        __syncthreads();   // all waves done reading xf

        if (layer < 5){
            float bias0 = bs[layer*256 + n0];
            float bias1 = bs[layer*256 + n1];
            #pragma unroll
            for (int mt = 0; mt < 8; ++mt){
                #pragma unroll
                for (int r = 0; r < 4; ++r){
                    int row = 16*mt + 4*lq + r;      // C/D: col=lane&15, row=(lane>>4)*4+reg
                    xf[XIDX(row, n0)] = (half_t)tanh_fast(mac[mt][0][r] + bias0);
                    xf[XIDX(row, n1)] = (half_t)tanh_fast(mac[mt][1][r] + bias1);
                }
            }
            __syncthreads();
        } else {
            float bias0 = bs[5*256 + n0];
            float bias1 = bs[5*256 + n1];
            float w0 = Wout[n0];
            float w1 = Wout[n1];
            float part = 0.f;
            #pragma unroll
            for (int mt = 0; mt < 8; ++mt){
                #pragma unroll
                for (int r = 0; r < 4; ++r){
                    part = fmaf(tanh_fast(mac[mt][0][r] + bias0), w0, part);
                    part = fmaf(tanh_fast(mac[mt][1][r] + bias1), w1, part);
                }
            }
            #pragma unroll
            for (int s = 1; s < 64; s <<= 1) part += __shfl_xor(part, s);
            if (lane == 0) redbuf[wid] = part;
            __syncthreads();
            if (tid == 0){
                float s = 0.f;
                #pragma unroll
                for (int i = 0; i < 8; ++i) s += redbuf[i];
                out[bk] = s + 128.0f * bout[0];
            }
        }
    }
}

extern "C" void kernel_launch(void* const* d_in, const int* in_sizes, int n_in,
                              void* d_out, int out_size, void* d_ws, size_t ws_size,
                              hipStream_t stream)
{
    (void)in_sizes; (void)n_in; (void)out_size; (void)d_ws; (void)ws_size;
    const float* ctx  = (const float*)d_in[0];
    const float* Ws   = (const float*)d_in[1];
    const float* bs   = (const float*)d_in[2];
    const float* Wout = (const float*)d_in[3];
    const float* bout = (const float*)d_in[4];
    float* out = (float*)d_out;

    const int smem_bytes = 128*64*4*2 + 128*4 + 128*4 + 128*4 + 8*4;  // 67104 B -> 2 WGs/CU
    hipFuncSetAttribute(reinterpret_cast<const void*>(fused_mlp_som),
                        hipFuncAttributeMaxDynamicSharedMemorySize, smem_bytes);
    fused_mlp_som<<<dim3(4096), dim3(512), smem_bytes, stream>>>(ctx, Ws, bs, Wout, bout, out);
}